// Round 1
// 204.171 us; speedup vs baseline: 1.1477x; 1.1477x over previous
//
#include <hip/hip_runtime.h>
#include <hip/hip_fp16.h>
#include <math.h>

#define NN 100000
#define NE 1600000
#define KF 48
#define NEDGE_ALL (2 * NE)

#define BKT_NODES 128                    // nodes per bucket (dst >> 7)
#define NBKT_PER  782                    // ceil(100000/128)
#define NBKT      1564                   // pos buckets then neg buckets
#define PACK_EPB  4096                   // edges per pack block (private region size)
#define NPB       782                    // pack blocks = ceil(3.2M / 4096)
#define OT2       1566                   // offT row stride (>= NBKT+1, even)
#define CAP2      2432                   // per-bucket srt capacity (mean 2046 + >8 sigma)
#define KSTG      10                     // staging registers per thread (10*256 >= CAP2)

typedef _Float16 half2v __attribute__((ext_vector_type(2)));
typedef _Float16 half4v __attribute__((ext_vector_type(4)));
typedef _Float16 half8v __attribute__((ext_vector_type(8)));

#if defined(__has_builtin)
#if __has_builtin(__builtin_amdgcn_fdot2)
#define HAVE_FDOT2 1
#endif
#endif

__device__ __forceinline__ void acc_pair(float& ax, float& ay, half2v v)
{
#ifdef HAVE_FDOT2
    ax = __builtin_amdgcn_fdot2(v, (half2v){(_Float16)1.f, (_Float16)0.f}, ax, false);
    ay = __builtin_amdgcn_fdot2(v, (half2v){(_Float16)0.f, (_Float16)1.f}, ay, false);
#else
    ax += (float)v.x;
    ay += (float)v.y;
#endif
}

// ---------------- phase 1: fused z-GEMM + LDS-sorted block-private pack -------------
// Round-12 change: scatter-add commutes with the first linear layer, so we
// precompute za = x@W1a + b1 (fp32), zb = x@W1b, zc = x@W1c (fp16, [N,16]).
// The edge gather then moves 32B/edge instead of 96B/edge, and layer-1 of the
// MLP becomes elementwise. The old f32->f16 cvt of x is replaced by this
// z-GEMM (weights broadcast from LDS; ~2300 FMA/node, hidden under pack).
__global__ __launch_bounds__(512) void pack_kernel(
    const float* __restrict__ x,
    const int* __restrict__ ei_pos,
    const int* __restrict__ ei_neg,
    const float* __restrict__ W1,        // [144,16] row-major
    const float* __restrict__ b1,        // [16]
    unsigned short* __restrict__ offT,   // [NPB * OT2], row r = pack-block r's bucket starts
    unsigned* __restrict__ plist,        // [NPB * PACK_EPB]
    float* __restrict__ za,              // [NN*16] fp32 (x@W1a + b1)
    __half* __restrict__ zbh,            // [(NN+2)*16] fp16 (x@W1b) + zero sentinels
    __half* __restrict__ zch)            // [(NN+2)*16] fp16 (x@W1c) + zero sentinels
{
    __shared__ int cnt[NBKT];            // hist -> becomes cursor
    __shared__ int ps[391];              // 4-compressed scan
    __shared__ unsigned stage[PACK_EPB]; // 16 KB sorted staging
    __shared__ float sW1[144 * 16];      // 9.2 KB weights (broadcast reads)
    __shared__ float sb1[16];

    const int t = threadIdx.x;
    for (int i = t; i < 144 * 16; i += 512) sW1[i] = W1[i];
    if (t < 16) sb1[t] = b1[t];
    for (int i = t; i < NBKT; i += 512) cnt[i] = 0;
    __syncthreads();

    // --- fused z-GEMM: one thread per node (blocks 0..195 do the work) ---
    {
        const int n = blockIdx.x * 512 + t;
        if (n < NN + 2) {
            float aA[16], aB[16], aC[16];
#pragma unroll
            for (int j = 0; j < 16; ++j) { aA[j] = sb1[j]; aB[j] = 0.f; aC[j] = 0.f; }
            if (n < NN) {
                const float4* __restrict__ x4 = (const float4*)(x + (long)n * KF);
                for (int i4 = 0; i4 < 12; ++i4) {
                    float4 v = x4[i4];
                    float vv[4] = {v.x, v.y, v.z, v.w};
#pragma unroll
                    for (int c = 0; c < 4; ++c) {
                        const int f = i4 * 4 + c;
                        const float* wA = &sW1[f * 16];
                        const float* wB = &sW1[(48 + f) * 16];
                        const float* wC = &sW1[(96 + f) * 16];
                        const float s = vv[c];
#pragma unroll
                        for (int j = 0; j < 16; ++j) {
                            aA[j] += s * wA[j];
                            aB[j] += s * wB[j];
                            aC[j] += s * wC[j];
                        }
                    }
                }
                float4* za4 = (float4*)(za + (long)n * 16);
#pragma unroll
                for (int j4 = 0; j4 < 4; ++j4)
                    za4[j4] = make_float4(aA[4*j4], aA[4*j4+1], aA[4*j4+2], aA[4*j4+3]);
            }
            half8v hb0, hb1, hc0, hc1;
#pragma unroll
            for (int j = 0; j < 8; ++j) {
                hb0[j] = (_Float16)aB[j];     hb1[j] = (_Float16)aB[8 + j];
                hc0[j] = (_Float16)aC[j];     hc1[j] = (_Float16)aC[8 + j];
            }
            half8v* zb8 = (half8v*)zbh;
            half8v* zc8 = (half8v*)zch;
            zb8[(long)n * 2 + 0] = hb0;  zb8[(long)n * 2 + 1] = hb1;
            zc8[(long)n * 2 + 0] = hc0;  zc8[(long)n * 2 + 1] = hc1;
        }
    }

    unsigned pk[8];
    int bk[8];
    const int blockBase = blockIdx.x * PACK_EPB;
#pragma unroll
    for (int j = 0; j < 8; ++j) {
        int e = blockBase + j * 512 + t;         // coalesced per j
        bk[j] = -1;
        if (e < NEDGE_ALL) {
            int list = e >= NE;
            int ee = list ? e - NE : e;
            const int* ei = list ? ei_neg : ei_pos;
            int src = ei[ee];
            int dst = ei[NE + ee];
            int b = list * NBKT_PER + (dst >> 7);
            bk[j] = b;
            pk[j] = ((unsigned)(dst & 127) << 17) | (unsigned)src;
            atomicAdd(&cnt[b], 1);               // native int LDS atomic
        }
    }
    __syncthreads();

    // exclusive scan over cnt[1564]: 4-compress to 391, H-S, expand
    int s0 = 0, s1 = 0, s2 = 0, s3 = 0;
    if (t < 391) {
        s0 = cnt[4 * t]; s1 = cnt[4 * t + 1]; s2 = cnt[4 * t + 2]; s3 = cnt[4 * t + 3];
        ps[t] = s0 + s1 + s2 + s3;
    }
    __syncthreads();
    for (int d = 1; d < 391; d <<= 1) {
        int v = (t < 391 && t >= d) ? ps[t - d] : 0;
        __syncthreads();
        if (t < 391) ps[t] += v;
        __syncthreads();
    }
    unsigned short* myrow = offT + (long)blockIdx.x * OT2;
    if (t < 391) {
        int base = t ? ps[t - 1] : 0;
        int o0 = base, o1 = o0 + s0, o2 = o1 + s1, o3 = o2 + s2;
        myrow[4 * t]     = (unsigned short)o0;
        myrow[4 * t + 1] = (unsigned short)o1;
        myrow[4 * t + 2] = (unsigned short)o2;
        myrow[4 * t + 3] = (unsigned short)o3;
        cnt[4 * t] = o0; cnt[4 * t + 1] = o1; cnt[4 * t + 2] = o2; cnt[4 * t + 3] = o3;
    }
    if (t == 390) myrow[NBKT] = (unsigned short)ps[390];   // total
    __syncthreads();

    // scatter into LDS staging (cheap), ...
#pragma unroll
    for (int j = 0; j < 8; ++j) {
        if (bk[j] >= 0) {
            int slot = atomicAdd(&cnt[bk[j]], 1);    // LDS cursor
            stage[slot] = pk[j];
        }
    }
    __syncthreads();

    // ... then stream out fully coalesced (uint4 = 16B/lane)
    {
        const uint4* __restrict__ st4 = (const uint4*)stage;
        uint4* __restrict__ out4 = (uint4*)(plist + (long)blockIdx.x * PACK_EPB);
#pragma unroll
        for (int j = 0; j < 2; ++j)
            out4[j * 512 + t] = st4[j * 512 + t];
    }
}

// -------- phase 2: register staging (binsearch) + LDS sort + 16-wide gather --------
// Staging/sort machinery UNCHANGED from round 11; payload is now 16 fp16 per
// edge (32B). 4 lanes per edge (half4 each), 16 edges per wave-iteration so
// the per-node granularity matches average degree (16) like before.
__global__ __launch_bounds__(256) void gather_kernel(
    const __half* __restrict__ zbh,
    const __half* __restrict__ zch,
    const unsigned* __restrict__ plist,
    const unsigned short* __restrict__ offT,
    float* __restrict__ hpos,            // [NN*16] fp32
    float* __restrict__ hneg)            // [NN*16] fp32
{
    __shared__ unsigned srt[CAP2];       // 9.5 KB (reused as rl[] scratch first)
    __shared__ int rb[NPB + 2];          // 3.1 KB run-base exclusive scan
    __shared__ unsigned short rsL[NPB];  // 1.6 KB run source starts
    __shared__ int tmp[196];             // 0.8 KB 4-compressed scan
    __shared__ int nh[BKT_NODES];
    __shared__ int starts[BKT_NODES];
    __shared__ int ends[BKT_NODES];
    __shared__ int cur2[BKT_NODES];

    const int b = blockIdx.x;
    const int t = threadIdx.x;

    for (int r = t; r < NPB; r += 256) {
        int s = offT[(long)r * OT2 + b];
        int e = offT[(long)r * OT2 + b + 1];
        rsL[r] = (unsigned short)s;
        srt[r] = (unsigned)(e - s);      // rl scratch
    }
    if (t < BKT_NODES) nh[t] = 0;
    __syncthreads();

    int s0 = 0, s1 = 0, s2 = 0, s3 = 0;
    if (t < 196) {
        int i0 = 4 * t;
        s0 = (i0     < NPB) ? (int)srt[i0]     : 0;
        s1 = (i0 + 1 < NPB) ? (int)srt[i0 + 1] : 0;
        s2 = (i0 + 2 < NPB) ? (int)srt[i0 + 2] : 0;
        s3 = (i0 + 3 < NPB) ? (int)srt[i0 + 3] : 0;
        tmp[t] = s0 + s1 + s2 + s3;
    }
    __syncthreads();
    for (int d = 1; d < 196; d <<= 1) {
        int v = (t < 196 && t >= d) ? tmp[t - d] : 0;
        __syncthreads();
        if (t < 196) tmp[t] += v;
        __syncthreads();
    }
    if (t < 196) {
        int base = t ? tmp[t - 1] : 0;
        int i0 = 4 * t;
        if (i0     <= NPB) rb[i0]     = base;
        if (i0 + 1 <= NPB) rb[i0 + 1] = base + s0;
        if (i0 + 2 <= NPB) rb[i0 + 2] = base + s0 + s1;
        if (i0 + 3 <= NPB) rb[i0 + 3] = base + s0 + s1 + s2;
    }
    __syncthreads();
    int cb = rb[NPB];
    if (cb > CAP2) cb = CAP2;

    unsigned held[KSTG];
#pragma unroll
    for (int k = 0; k < KSTG; ++k) {
        int i = t + k * 256;
        held[k] = 0;
        if (i < cb) {
            int lo = 0, hi = NPB - 1;
#pragma unroll
            for (int it = 0; it < 10; ++it) {
                int mid = (lo + hi + 1) >> 1;
                bool ge = (rb[mid] <= i);
                lo = ge ? mid : lo;
                hi = ge ? hi : mid - 1;
            }
            unsigned p = plist[(long)lo * PACK_EPB + rsL[lo] + (i - rb[lo])];
            held[k] = p;
            atomicAdd(&nh[p >> 17], 1);
        }
    }
    __syncthreads();

    for (int d = 1; d < BKT_NODES; d <<= 1) {
        int v = 0;
        if (t < BKT_NODES && t >= d) v = nh[t - d];
        __syncthreads();
        if (t < BKT_NODES) nh[t] += v;
        __syncthreads();
    }
    if (t < BKT_NODES) {
        int e_ = min(nh[t], CAP2);
        int s_ = t ? min(nh[t - 1], CAP2) : 0;
        starts[t] = s_;
        ends[t] = e_;
        cur2[t] = s_;
    }
    __syncthreads();

#pragma unroll
    for (int k = 0; k < KSTG; ++k) {
        int i = t + k * 256;
        if (i < cb) {
            unsigned p = held[k];
            int slot = atomicAdd(&cur2[p >> 17], 1);
            if (slot < CAP2) srt[slot] = p;
        }
    }
    __syncthreads();

    const int wave = t >> 6, lane = t & 63;
    const int g = lane >> 2;                 // 0..15 edge slot
    const int sub = lane & 3;                // 0..3 feature quad
    const int list = b >= NBKT_PER;
    const int nb = list ? b - NBKT_PER : b;
    float* o = list ? hneg : hpos;
    const half4v* __restrict__ z4 = (const half4v*)(list ? zch : zbh);

    for (int n = wave; n < BKT_NODES; n += 4) {
        int gn = nb * BKT_NODES + n;
        if (gn >= NN) continue;
        int s = starts[n], e = ends[n];
        float a0 = 0.f, a1 = 0.f, a2 = 0.f, a3 = 0.f;
        for (int j = s; j < e; j += 16) {
            int i0 = j + g;
            int q = (i0 < e) ? (int)(srt[i0 < CAP2 ? i0 : 0] & 0x1FFFFu) : NN;
            half4v v = z4[q * 4 + sub];
            acc_pair(a0, a1, (half2v){v.x, v.y});
            acc_pair(a2, a3, (half2v){v.z, v.w});
        }
        a0 += __shfl_xor(a0, 4); a0 += __shfl_xor(a0, 8); a0 += __shfl_xor(a0, 16); a0 += __shfl_xor(a0, 32);
        a1 += __shfl_xor(a1, 4); a1 += __shfl_xor(a1, 8); a1 += __shfl_xor(a1, 16); a1 += __shfl_xor(a1, 32);
        a2 += __shfl_xor(a2, 4); a2 += __shfl_xor(a2, 8); a2 += __shfl_xor(a2, 16); a2 += __shfl_xor(a2, 32);
        a3 += __shfl_xor(a3, 4); a3 += __shfl_xor(a3, 8); a3 += __shfl_xor(a3, 16); a3 += __shfl_xor(a3, 32);
        if (g == 0) {
            float4* o4 = (float4*)o;
            o4[(long)gn * 4 + sub] = make_float4(a0, a1, a2, a3);
        }
    }
}

// ---------------- phase 3: elementwise tanh + tiny W2 matmul + softmax --------------
// Layer 1 collapsed to h = tanh(za + hpos + hneg) by the z-precompute.
__global__ __launch_bounds__(256) void mlp2_kernel(
    const float* __restrict__ za,
    const float* __restrict__ hpos,
    const float* __restrict__ hneg,
    const float* __restrict__ W2,   // [16,48]
    const float* __restrict__ b2,
    float* __restrict__ out)
{
    __shared__ float sW2[16 * 48];
    __shared__ float sb2[48];
    for (int i = threadIdx.x; i < 16 * 48; i += 256) sW2[i] = W2[i];
    if (threadIdx.x < 48) sb2[threadIdx.x] = b2[threadIdx.x];
    __syncthreads();

    const int n = blockIdx.x * 256 + threadIdx.x;
    if (n >= NN) return;

    const float4* A = (const float4*)(za   + (long)n * 16);
    const float4* P = (const float4*)(hpos + (long)n * 16);
    const float4* Q = (const float4*)(hneg + (long)n * 16);
    float h[16];
#pragma unroll
    for (int j4 = 0; j4 < 4; ++j4) {
        float4 a = A[j4], p = P[j4], q = Q[j4];
        h[4 * j4 + 0] = tanhf(a.x + p.x + q.x);
        h[4 * j4 + 1] = tanhf(a.y + p.y + q.y);
        h[4 * j4 + 2] = tanhf(a.z + p.z + q.z);
        h[4 * j4 + 3] = tanhf(a.w + p.w + q.w);
    }

    float C[KF];
#pragma unroll
    for (int k = 0; k < KF; ++k) C[k] = sb2[k];
    for (int j = 0; j < 16; ++j) {
        const float hv = h[j];
        const float* w = &sW2[j * KF];
#pragma unroll
        for (int k = 0; k < KF; ++k) C[k] += hv * w[k];
    }

    float m = C[0];
#pragma unroll
    for (int k = 1; k < KF; ++k) m = fmaxf(m, C[k]);
    float ssum = 0.f;
#pragma unroll
    for (int k = 0; k < KF; ++k) { C[k] = expf(C[k] - m); ssum += C[k]; }
    const float inv = 1.0f / ssum;

    float4* po = (float4*)(out + (long)n * KF);
#pragma unroll
    for (int k4 = 0; k4 < 12; ++k4)
        po[k4] = make_float4(C[4*k4] * inv, C[4*k4+1] * inv, C[4*k4+2] * inv, C[4*k4+3] * inv);
}

// ============== fallback path (if ws too small): unchanged round-11 ==============
__global__ __launch_bounds__(256) void scatter2_kernel(
    const float* __restrict__ x,
    const int* __restrict__ ei_pos,
    const int* __restrict__ ei_neg,
    float* acc_pos,
    float* acc_neg)
{
    const int list = blockIdx.y;
    const int* ei = list ? ei_neg : ei_pos;
    float* acc = list ? acc_neg : acc_pos;

    long t = (long)blockIdx.x * blockDim.x + threadIdx.x;
    const long total = (long)NE * 12;
    if (t >= total) return;

    int e = (int)(t / 12);
    int r = (int)(t - (long)e * 12);
    int k4 = r * 4;

    int src = ei[e];
    int dst = ei[NE + e];

    const float4 v = *(const float4*)(x + (long)src * KF + k4);
    float* p = acc + (long)dst * KF + k4;

    unsafeAtomicAdd(p + 0, v.x);
    unsafeAtomicAdd(p + 1, v.y);
    unsafeAtomicAdd(p + 2, v.z);
    unsafeAtomicAdd(p + 3, v.w);
}

// full MLP for the fallback path (xpos aliases out; reads own row before write)
__global__ __launch_bounds__(256) void mlp_softmax_kernel(
    const float* __restrict__ x,
    const float* xpos,
    const float* __restrict__ xneg,
    const float* __restrict__ W1,   // [144,16]
    const float* __restrict__ b1,
    const float* __restrict__ W2,   // [16,48]
    const float* __restrict__ b2,
    float* out)
{
    __shared__ float sW1[144 * 16];
    __shared__ float sW2[16 * 48];
    __shared__ float sb1[16];
    __shared__ float sb2[48];

    for (int i = threadIdx.x; i < 144 * 16; i += blockDim.x) sW1[i] = W1[i];
    for (int i = threadIdx.x; i < 16 * 48;  i += blockDim.x) sW2[i] = W2[i];
    if (threadIdx.x < 16) sb1[threadIdx.x] = b1[threadIdx.x];
    if (threadIdx.x < 48) sb2[threadIdx.x] = b2[threadIdx.x];
    __syncthreads();

    const int n = blockIdx.x * blockDim.x + threadIdx.x;
    if (n >= NN) return;

    float h[16];
#pragma unroll
    for (int j = 0; j < 16; ++j) h[j] = sb1[j];

    const float* srcs[3];
    srcs[0] = x    + (long)n * KF;
    srcs[1] = xpos + (long)n * KF;
    srcs[2] = xneg + (long)n * KF;

    for (int s = 0; s < 3; ++s) {
        const float* px = srcs[s];
        for (int i = 0; i < KF; ++i) {
            const float v = px[i];
            const float* w = &sW1[(s * KF + i) * 16];
#pragma unroll
            for (int j = 0; j < 16; ++j) h[j] += v * w[j];
        }
    }
#pragma unroll
    for (int j = 0; j < 16; ++j) h[j] = tanhf(h[j]);

    float C[KF];
#pragma unroll
    for (int k = 0; k < KF; ++k) C[k] = sb2[k];
    for (int j = 0; j < 16; ++j) {
        const float hv = h[j];
        const float* w = &sW2[j * KF];
#pragma unroll
        for (int k = 0; k < KF; ++k) C[k] += hv * w[k];
    }

    float m = C[0];
#pragma unroll
    for (int k = 1; k < KF; ++k) m = fmaxf(m, C[k]);
    float ssum = 0.f;
#pragma unroll
    for (int k = 0; k < KF; ++k) { C[k] = expf(C[k] - m); ssum += C[k]; }
    const float inv = 1.0f / ssum;

    float* po = out + (long)n * KF;
#pragma unroll
    for (int k = 0; k < KF; ++k) po[k] = C[k] * inv;
}

extern "C" void kernel_launch(void* const* d_in, const int* in_sizes, int n_in,
                              void* d_out, int out_size, void* d_ws, size_t ws_size,
                              hipStream_t stream)
{
    const float* x      = (const float*)d_in[0];
    const int*   ei_pos = (const int*)  d_in[1];
    const int*   ei_neg = (const int*)  d_in[2];
    const float* W1     = (const float*)d_in[3];
    const float* b1     = (const float*)d_in[4];
    const float* W2     = (const float*)d_in[5];
    const float* b2     = (const float*)d_in[6];

    float* out = (float*)d_out;

    const size_t h_bytes     = (size_t)NN * 16 * sizeof(float);               // 6.4 MB
    const size_t za_bytes    = (size_t)NN * 16 * sizeof(float);               // 6.4 MB
    const size_t zh_bytes    = (size_t)(NN + 2) * 16 * sizeof(__half);        // 3.2 MB
    const size_t plist_bytes = (size_t)NPB * PACK_EPB * sizeof(unsigned);     // 12.8 MB
    const size_t offT_bytes  = (size_t)NPB * OT2 * sizeof(unsigned short);    // 2.45 MB

    // ws layout: [hpos | hneg | za | zbh | zch | plist | offT]  (~40.9 MB)
    size_t off = 0;
    char* ws = (char*)d_ws;
    float*          hpos  = (float*)(ws + off);          off += h_bytes;
    float*          hneg  = (float*)(ws + off);          off += h_bytes;
    float*          za    = (float*)(ws + off);          off += za_bytes;
    __half*         zbh   = (__half*)(ws + off);         off += zh_bytes;
    __half*         zch   = (__half*)(ws + off);         off += zh_bytes;
    unsigned*       plist = (unsigned*)(ws + off);       off += plist_bytes;
    unsigned short* offT  = (unsigned short*)(ws + off); off += offT_bytes;
    const size_t needed = off;

    if (ws_size >= needed) {
        pack_kernel<<<NPB, 512, 0, stream>>>(x, ei_pos, ei_neg, W1, b1, offT, plist, za, zbh, zch);
        gather_kernel<<<NBKT, 256, 0, stream>>>(zbh, zch, plist, offT, hpos, hneg);
        mlp2_kernel<<<(NN + 255) / 256, 256, 0, stream>>>(za, hpos, hneg, W2, b2, out);
    } else {
        // fallback: atomic scatter + full MLP (xpos aliases out)
        float* xpos = (float*)d_out;
        float* xneg = (float*)d_ws;      // needs 19.2 MB
        const size_t acc_bytes = (size_t)NN * KF * sizeof(float);
        hipMemsetAsync(xpos, 0, acc_bytes, stream);
        hipMemsetAsync(xneg, 0, acc_bytes, stream);
        const long total = (long)NE * 12;
        dim3 grid((unsigned)((total + 255) / 256), 2, 1);
        scatter2_kernel<<<grid, 256, 0, stream>>>(x, ei_pos, ei_neg, xpos, xneg);
        mlp_softmax_kernel<<<(NN + 255) / 256, 256, 0, stream>>>(x, xpos, xneg, W1, b1, W2, b2, out);
    }
}